// Round 9
// baseline (317.152 us; speedup 1.0000x reference)
//
#include <hip/hip_runtime.h>
#include <hip/hip_bf16.h>

#define SEQ 512
#define HID 768
#define P2  46
#define MT  16              // rows per block
#define BLK 256             // 4 waves: all issue DMA; waves 0-2 compute + q
#define NSTEP (HID / 32)    // 24 MFMA K-steps

typedef short bf16x8 __attribute__((ext_vector_type(8)));
typedef float f32x4  __attribute__((ext_vector_type(4)));

// packed-pair friendly cast: lowers to v_cvt_pk_bf16_f32 (RNE)
__device__ __forceinline__ unsigned short fcvt(float f) {
  __hip_bfloat16 x = __float2bfloat16(f);
  return *reinterpret_cast<unsigned short*>(&x);
}

__device__ __forceinline__ void async_ld16(const void* g, void* l) {
  // global -> LDS DMA, 16 B/lane; LDS dest = wave-uniform base + lane*16
  __builtin_amdgcn_global_load_lds(
      (const __attribute__((address_space(1))) unsigned int*)g,
      (__attribute__((address_space(3))) unsigned int*)l, 16, 0, 0);
}

// Single kernel, single barrier.
//  1) all 4 waves DMA the 16x768 fp32 h tile (source-side XOR swizzle).
//  2) waves 0-2, during the DMA drain window: load their W rows fp32 from L2,
//     cvt->bf16 fragments for MFMA, AND fma the same fp32 W against
//     s = h[i0]+h[i1] slices -> exact fp32 q, reduced in-wave (shfl butterfly).
//  3) barrier (drains DMA).  4) pure LDS->cvt->MFMA loop.  5) fused epilogue.
__global__ __launch_bounds__(BLK, 3) void fused_kernel(
    const float* __restrict__ h, const int* __restrict__ ids,
    const int* __restrict__ mask, const float* __restrict__ W,
    const float* __restrict__ bias, float* __restrict__ out) {
  // fp32 tile [16 rows][768]; within a row, 32B group gg lives at
  // (gg&~7)|((gg^row)&7)  (XOR involution applied to the DMA *source*)
  __shared__ __align__(16) float hA[MT][HID];   // 48 KB -> 3 blocks/CU

  const int tid  = threadIdx.x;
  const int lane = tid & 63, wv = tid >> 6;
  const int mr = lane & 15, qd = lane >> 4;
  const int row0 = blockIdx.x * MT;
  const int b    = row0 >> 9;                 // SEQ = 512

  // ---- 1) issue 12 DMA instrs/wave (48 x 1KB = whole 48 KB tile) ----
  const float* hblk = h + (size_t)row0 * HID;
  #pragma unroll
  for (int j = 0; j < 12; ++j) {
    const int r   = (wv << 2) + j / 3;        // row 0..15 (folds per-iter)
    const int seg = j % 3;                    // 1KB segment of the 3KB row
    int c  = (seg << 6) + lane;               // 16B chunk within row, 0..191
    int gg = c >> 1;                          // 32B group 0..95
    int gs = (gg & ~7) | ((gg ^ r) & 7);      // swizzled source group
    const float* src = hblk + (size_t)r * HID + ((gs << 1) | (c & 1)) * 4;
    async_ld16(src, &hA[r][seg << 8]);        // dest wave-uniform, linear
  }

  // ---- 2) W preload + exact-fp32 q, overlapped with the DMA window ----
  const int nt = wv;                          // n-tile 0..2
  bf16x8 wf[NSTEP];
  f32x4 acc = f32x4{0.f, 0.f, 0.f, 0.f};
  int mk = 0, p0 = 0, grow = 0;
  float bv[4], qv[4];
  if (wv < 3) {
    const int p = (nt << 4) + mr;             // this lane's W row (0..47)
    const int wrow = (p > P2 - 1) ? (P2 - 1) : p;   // clamp: no OOB W read
    const float* wp = W + (size_t)wrow * HID + (qd << 3);
    const int i0 = ids[b * 2 + 0], i1 = ids[b * 2 + 1];
    const float* h0p = h + ((size_t)b * SEQ + i0) * HID + (qd << 3);
    const float* h1p = h + ((size_t)b * SEQ + i1) * HID + (qd << 3);

    float qa = 0.f, qb = 0.f;                 // 2 accums to shorten FMA chain
    #pragma unroll
    for (int s = 0; s < NSTEP; ++s) {
      float4 w0 = *(const float4*)(wp  + (s << 5));
      float4 w1 = *(const float4*)(wp  + (s << 5) + 4);
      float4 a0 = *(const float4*)(h0p + (s << 5));
      float4 a1 = *(const float4*)(h0p + (s << 5) + 4);
      float4 b0 = *(const float4*)(h1p + (s << 5));
      float4 b1 = *(const float4*)(h1p + (s << 5) + 4);
      wf[s] = bf16x8{ (short)fcvt(w0.x), (short)fcvt(w0.y),
                      (short)fcvt(w0.z), (short)fcvt(w0.w),
                      (short)fcvt(w1.x), (short)fcvt(w1.y),
                      (short)fcvt(w1.z), (short)fcvt(w1.w) };
      qa += w0.x * (a0.x + b0.x);  qb += w0.y * (a0.y + b0.y);
      qa += w0.z * (a0.z + b0.z);  qb += w0.w * (a0.w + b0.w);
      qa += w1.x * (a1.x + b1.x);  qb += w1.y * (a1.y + b1.y);
      qa += w1.z * (a1.z + b1.z);  qb += w1.w * (a1.w + b1.w);
    }
    float qfull = qa + qb;                    // partial over k%32 in [qd*8,qd*8+8)
    qfull += __shfl_xor(qfull, 16, 64);       // reduce across qd groups
    qfull += __shfl_xor(qfull, 32, 64);       // now all lanes: q[nt*16 + mr]

    grow = row0 + mr;                         // this lane's seq row (D col=mr)
    mk   = mask[grow];
    p0   = (nt << 4) + (qd << 2);
    #pragma unroll
    for (int i = 0; i < 4; ++i) {
      bv[i] = (p0 + i < P2) ? bias[p0 + i] : 0.f;
      qv[i] = __shfl(qfull, (qd << 2) + i, 64);   // lane qd*4+i holds q[p0+i]
    }
  }

  __syncthreads();                            // drains DMAs (vmcnt 0) + sync
  if (wv >= 3) return;

  // ---- 3) K loop: pure LDS -> cvt_pk -> MFMA (no global dependency) ----
  #pragma unroll
  for (int s = 0; s < NSTEP; ++s) {
    int gg = (s << 2) + qd;
    int gs = (gg & ~7) | ((gg ^ mr) & 7);     // same XOR, row = mr
    const float* fp = &hA[mr][gs << 3];       // 32B group = 8 floats
    float4 a0 = *(const float4*)fp;
    float4 a1 = *(const float4*)(fp + 4);
    bf16x8 hb = { (short)fcvt(a0.x), (short)fcvt(a0.y),
                  (short)fcvt(a0.z), (short)fcvt(a0.w),
                  (short)fcvt(a1.x), (short)fcvt(a1.y),
                  (short)fcvt(a1.z), (short)fcvt(a1.w) };
    acc = __builtin_amdgcn_mfma_f32_16x16x32_bf16(wf[s], hb, acc, 0, 0, 0);
  }

  // ---- 4) epilogue: D row = p (qd*4+i), D col = seq row (mr) ----
  float* orow = out + (size_t)grow * P2;
  float o[4];
  #pragma unroll
  for (int i = 0; i < 4; ++i) {
    float x = acc[i] + bv[i] + (mk ? qv[i] : 0.f);
    float sg = 1.f / (1.f + __expf(-x));
    sg *= sg; sg *= sg;                       // sigmoid^4
    o[i] = sg;
  }
  if (p0 + 1 < P2) *(float2*)(orow + p0)     = make_float2(o[0], o[1]);
  if (p0 + 3 < P2) *(float2*)(orow + p0 + 2) = make_float2(o[2], o[3]);
}

extern "C" void kernel_launch(void* const* d_in, const int* in_sizes, int n_in,
                              void* d_out, int out_size, void* d_ws, size_t ws_size,
                              hipStream_t stream) {
  const float* h    = (const float*)d_in[0];   // [64,512,768] fp32
  const int*   ids  = (const int*)d_in[1];     // [64,2]
  const int*   mask = (const int*)d_in[2];     // [64,512]
  const float* W    = (const float*)d_in[3];   // [46,768]
  const float* bias = (const float*)d_in[4];   // [46]
  float* out = (float*)d_out;                  // [64,512,46] fp32

  fused_kernel<<<dim3((64 * SEQ) / MT), BLK, 0, stream>>>(h, ids, mask, W, bias, out);
}